// Round 3
// baseline (483.922 us; speedup 1.0000x reference)
//
#include <hip/hip_runtime.h>
#include <stdint.h>

// ---------------- problem constants ----------------
#define B_ROWS  4096
#define F_FIELDS 39
#define NPAIR   741
#define XCON_K  23712          // 2*741*16
#define KP      23744          // padded to multiple of 64
#define NP      512            // padded hidden width (real 400)
#define HID     400
#define SPLITK0 8
#define KITERS0 (KP/64)        // 371

// ---------------- ws layout (bytes) ----------------
#define OFF_XCON 0ull
#define SZ_XCON  ((size_t)B_ROWS * KP * 2)        // 194,510,848
#define OFF_W0B  (OFF_XCON + SZ_XCON)
#define SZ_W0B   ((size_t)NP * KP * 2)            // 24,313,856
#define OFF_W1B  (OFF_W0B + SZ_W0B)
#define SZ_WSM   ((size_t)NP * NP * 2)            // 524,288
#define OFF_W2B  (OFF_W1B + SZ_WSM)
#define OFF_HPRE (OFF_W2B + SZ_WSM)
#define SZ_HPRE  ((size_t)B_ROWS * NP * 4)        // 8,388,608
#define OFF_HN   (OFF_HPRE + SZ_HPRE)
#define SZ_HN    ((size_t)B_ROWS * NP * 2)        // 4,194,304
#define OFF_STATS (OFF_HN + SZ_HN)                // colsum/colsumsq 512 f32 each
#define WS_NEEDED (OFF_STATS + 8192)

// ---------------- helpers ----------------
__device__ __forceinline__ unsigned short f2bf(float f) {
    union { float f; unsigned u; } v; v.f = f;
    unsigned r = (v.u + 0x7FFFu + ((v.u >> 16) & 1u)) >> 16;
    return (unsigned short)r;
}
__device__ __forceinline__ float bf2f(unsigned short h) {
    union { unsigned u; float f; } v; v.u = ((unsigned)h) << 16;
    return v.f;
}
__device__ __forceinline__ void gl_lds16(const void* g, void* l) {
    __builtin_amdgcn_global_load_lds(
        (const __attribute__((address_space(1))) void*)g,
        (__attribute__((address_space(3))) void*)l, 16, 0, 0);
}

typedef __bf16 bf16x8 __attribute__((ext_vector_type(8)));
typedef float  floatx4 __attribute__((ext_vector_type(4)));

// ---------------- kernel 1: gather + SENet + bilinear -> x_con (bf16, K-padded) ----------------
__global__ __launch_bounds__(256) void build_xcon(
    const int* __restrict__ x, const float* __restrict__ emb,
    const float* __restrict__ w1, const float* __restrict__ b1,
    const float* __restrict__ w2, const float* __restrict__ b2,
    const float* __restrict__ Wb1, const float* __restrict__ Wb2,
    unsigned short* __restrict__ xcon)
{
    __shared__ float xe[624], pp[2][624];
    __shared__ float zz[40], tt[40], aa[40];
    __shared__ short itab[NPAIR], jtab[NPAIR];
    const int b = blockIdx.x, tid = threadIdx.x;

    // pair tables via closed form: i = smallest i with cum(i+1) > p, cum(i) = sum_{t<i}(38-t)
    for (int p = tid; p < NPAIR; p += 256) {
        float fp = (float)p;
        int i = (int)(38.5f - sqrtf(38.5f * 38.5f - 2.f * fp));   // approx
        // correct (handles fp rounding): cum(i) = i*(77-i)/2
        while (i > 0 && p < (i * (77 - i)) / 2) --i;
        while (p >= ((i + 1) * (76 - i)) / 2) ++i;
        itab[p] = (short)i;
        jtab[p] = (short)(i + 1 + (p - (i * (77 - i)) / 2));
    }
    // gather embeddings: xe[f][e] = emb[x[b,f] + 1000*f][e]  (float4)
    if (tid < 156) {
        int f = tid >> 2, e4 = (tid & 3) * 4;
        int row = x[b * F_FIELDS + f] + 1000 * f;
        *(float4*)&xe[f * 16 + e4] = *(const float4*)&emb[row * 16 + e4];
    }
    __syncthreads();
    if (tid < F_FIELDS) {                         // z = max over E
        float m = xe[tid * 16];
        for (int e = 1; e < 16; ++e) m = fmaxf(m, xe[tid * 16 + e]);
        zz[tid] = m;
    }
    __syncthreads();
    if (tid < F_FIELDS) {                         // t = relu(z @ w1.T + b1)
        float s = b1[tid];
        for (int g = 0; g < F_FIELDS; ++g) s += zz[g] * w1[tid * F_FIELDS + g];
        tt[tid] = fmaxf(s, 0.f);
    }
    __syncthreads();
    if (tid < F_FIELDS) {                         // a = relu(t @ w2.T + b2)
        float s = b2[tid];
        for (int g = 0; g < F_FIELDS; ++g) s += tt[g] * w2[tid * F_FIELDS + g];
        aa[tid] = fmaxf(s, 0.f);
    }
    __syncthreads();
    for (int idx = tid; idx < 624; idx += 256) {  // proj = xe @ Wb.T for both Wb
        int f = idx >> 4, d = idx & 15;
        float s1 = 0.f, s2 = 0.f;
        for (int e = 0; e < 16; ++e) {
            float v = xe[f * 16 + e];
            s1 += v * Wb1[d * 16 + e];
            s2 += v * Wb2[d * 16 + e];
        }
        pp[0][idx] = s1; pp[1][idx] = s2;
    }
    __syncthreads();
    unsigned short* out = xcon + (size_t)b * KP;
    // 1482 chunks of 16 outputs (32B) + 2 zero-pad chunks
    for (int c = tid; c < 1484; c += 256) {
        if (c < 2 * NPAIR) {
            const int half = (c >= NPAIR);
            const int p = c - NPAIR * half;
            const int i = itab[p], j = jtab[p];
            const float f = half ? aa[i] * aa[j] : 1.f;
            const float* pr = &pp[half][i * 16];
            const float* xr = &xe[j * 16];
            unsigned short u[16];
#pragma unroll
            for (int e = 0; e < 16; ++e) u[e] = f2bf(f * pr[e] * xr[e]);
            uint4 v0, v1;
            v0.x = u[0] | ((unsigned)u[1] << 16);  v0.y = u[2] | ((unsigned)u[3] << 16);
            v0.z = u[4] | ((unsigned)u[5] << 16);  v0.w = u[6] | ((unsigned)u[7] << 16);
            v1.x = u[8] | ((unsigned)u[9] << 16);  v1.y = u[10] | ((unsigned)u[11] << 16);
            v1.z = u[12] | ((unsigned)u[13] << 16); v1.w = u[14] | ((unsigned)u[15] << 16);
            uint4* dst = (uint4*)(out + (half ? 11856 : 0) + p * 16);
            dst[0] = v0; dst[1] = v1;
        } else {
            uint4 z; z.x = z.y = z.z = z.w = 0u;
            ((uint4*)(out + XCON_K))[c - 2 * NPAIR] = z;
        }
    }
}

// ---------------- weight conversion (fp32 -> bf16, zero-padded) ----------------
__global__ __launch_bounds__(256) void cvt_w0(const float* __restrict__ w, unsigned short* __restrict__ o_) {
    const int o = blockIdx.x;   // 512 rows
    for (int k4 = threadIdx.x; k4 < KP / 4; k4 += 256) {
        const int k = k4 * 4;
        unsigned short u[4] = {0, 0, 0, 0};
        if (o < HID && k < XCON_K) {
            float4 v = *(const float4*)&w[(size_t)o * XCON_K + k];
            u[0] = f2bf(v.x); u[1] = f2bf(v.y); u[2] = f2bf(v.z); u[3] = f2bf(v.w);
        }
        uint2 pk; pk.x = u[0] | ((unsigned)u[1] << 16); pk.y = u[2] | ((unsigned)u[3] << 16);
        *(uint2*)&o_[(size_t)o * KP + k] = pk;
    }
}
__global__ __launch_bounds__(256) void cvt_wsm(const float* __restrict__ wa, const float* __restrict__ wb,
                                               unsigned short* __restrict__ oa, unsigned short* __restrict__ ob) {
    const int which = blockIdx.x >> 9;
    const int o = blockIdx.x & 511;
    const float* w = which ? wb : wa;
    unsigned short* o_ = which ? ob : oa;
    for (int k = threadIdx.x; k < NP; k += 256) {
        float v = (o < HID && k < HID) ? w[o * HID + k] : 0.f;
        o_[o * NP + k] = f2bf(v);
    }
}

// ---------------- GEMM0: 64x256 tile, split-K, atomic f32 epilogue ----------------
// C[M=4096, N=512](f32, +=) = A[M,KP] @ B[N,KP]^T
// 256 thr = 2x2 waves, each wave 32x128 (2x8 MFMAs) -> acc 64 AGPR -> 4 waves/SIMD
__global__ __launch_bounds__(256, 4) void gemm0(
    const unsigned short* __restrict__ A, const unsigned short* __restrict__ Bm,
    float* __restrict__ C, int kcnt)
{
    __shared__ __align__(16) unsigned short As[64 * 64];     // 8 KB
    __shared__ __align__(16) unsigned short Bs[256 * 64];    // 32 KB
    const int tid = threadIdx.x;
    const int m0 = blockIdx.y * 64, n0 = blockIdx.x * 256;
    int kb = blockIdx.z * kcnt;
    int ke = kb + kcnt; if (ke > KITERS0) ke = KITERS0;

    const unsigned short* Ag = A + (size_t)(m0 + (tid >> 3)) * KP + ((tid & 7) * 8);
    const unsigned short* Bg = Bm + (size_t)(n0 + (tid >> 3)) * KP + ((tid & 7) * 8);
    unsigned short* Asl = As + tid * 8;
    unsigned short* Bsl = Bs + tid * 8;

    const int wv = tid >> 6, ln = tid & 63;
    const int wm = (wv >> 1) * 32, wn = (wv & 1) * 128;
    const int l15 = ln & 15, lq = ln >> 4;

    floatx4 acc[2][8];
#pragma unroll
    for (int mi = 0; mi < 2; ++mi)
#pragma unroll
        for (int ni = 0; ni < 8; ++ni)
            acc[mi][ni] = (floatx4){0.f, 0.f, 0.f, 0.f};

    for (int kt = kb; kt < ke; ++kt) {
        const size_t ko = (size_t)kt * 64;
#pragma unroll
        for (int i = 0; i < 2; ++i)
            gl_lds16(Ag + (size_t)(i * 32) * KP + ko, Asl + i * 2048);
#pragma unroll
        for (int i = 0; i < 8; ++i)
            gl_lds16(Bg + (size_t)(i * 32) * KP + ko, Bsl + i * 2048);
        __syncthreads();
#pragma unroll
        for (int kk = 0; kk < 64; kk += 32) {
            bf16x8 af[2], bfr[8];
#pragma unroll
            for (int t = 0; t < 2; ++t)
                af[t] = *(const bf16x8*)(As + (wm + t * 16 + l15) * 64 + kk + lq * 8);
#pragma unroll
            for (int t = 0; t < 8; ++t)
                bfr[t] = *(const bf16x8*)(Bs + (wn + t * 16 + l15) * 64 + kk + lq * 8);
#pragma unroll
            for (int mi = 0; mi < 2; ++mi)
#pragma unroll
                for (int ni = 0; ni < 8; ++ni)
                    acc[mi][ni] = __builtin_amdgcn_mfma_f32_16x16x32_bf16(
                        af[mi], bfr[ni], acc[mi][ni], 0, 0, 0);
        }
        __syncthreads();
    }
#pragma unroll
    for (int mi = 0; mi < 2; ++mi)
#pragma unroll
        for (int ni = 0; ni < 8; ++ni) {
            const int col = n0 + wn + ni * 16 + l15;
            const int row0 = m0 + wm + mi * 16 + lq * 4;
#pragma unroll
            for (int r = 0; r < 4; ++r)
                atomicAdd(&C[(size_t)(row0 + r) * NP + col], acc[mi][ni][r]);
        }
}

// ---------------- GEMM1/2: 64x64 tile, K=512, direct store ----------------
__global__ __launch_bounds__(256) void gemm_small(
    const unsigned short* __restrict__ A, const unsigned short* __restrict__ Bm,
    float* __restrict__ C)
{
    __shared__ __align__(16) unsigned short As[64 * 64];
    __shared__ __align__(16) unsigned short Bs[64 * 64];
    const int tid = threadIdx.x;
    const int m0 = blockIdx.y * 64, n0 = blockIdx.x * 64;

    const unsigned short* Ag = A + (size_t)(m0 + (tid >> 3)) * NP + ((tid & 7) * 8);
    const unsigned short* Bg = Bm + (size_t)(n0 + (tid >> 3)) * NP + ((tid & 7) * 8);
    unsigned short* Asl = As + tid * 8;
    unsigned short* Bsl = Bs + tid * 8;

    const int wv = tid >> 6, ln = tid & 63;
    const int wm = (wv >> 1) * 32, wn = (wv & 1) * 32;
    const int l15 = ln & 15, lq = ln >> 4;

    floatx4 acc[2][2];
#pragma unroll
    for (int mi = 0; mi < 2; ++mi)
#pragma unroll
        for (int ni = 0; ni < 2; ++ni)
            acc[mi][ni] = (floatx4){0.f, 0.f, 0.f, 0.f};

    for (int kt = 0; kt < NP / 64; ++kt) {
        const size_t ko = (size_t)kt * 64;
#pragma unroll
        for (int i = 0; i < 2; ++i) {
            gl_lds16(Ag + (size_t)(i * 32) * NP + ko, Asl + i * 2048);
            gl_lds16(Bg + (size_t)(i * 32) * NP + ko, Bsl + i * 2048);
        }
        __syncthreads();
#pragma unroll
        for (int kk = 0; kk < 64; kk += 32) {
            bf16x8 af[2], bfr[2];
#pragma unroll
            for (int t = 0; t < 2; ++t) {
                af[t]  = *(const bf16x8*)(As + (wm + t * 16 + l15) * 64 + kk + lq * 8);
                bfr[t] = *(const bf16x8*)(Bs + (wn + t * 16 + l15) * 64 + kk + lq * 8);
            }
#pragma unroll
            for (int mi = 0; mi < 2; ++mi)
#pragma unroll
                for (int ni = 0; ni < 2; ++ni)
                    acc[mi][ni] = __builtin_amdgcn_mfma_f32_16x16x32_bf16(
                        af[mi], bfr[ni], acc[mi][ni], 0, 0, 0);
        }
        __syncthreads();
    }
#pragma unroll
    for (int mi = 0; mi < 2; ++mi)
#pragma unroll
        for (int ni = 0; ni < 2; ++ni) {
            const int col = n0 + wn + ni * 16 + l15;
            const int row0 = m0 + wm + mi * 16 + lq * 4;
#pragma unroll
            for (int r = 0; r < 4; ++r)
                C[(size_t)(row0 + r) * NP + col] = acc[mi][ni][r];
        }
}

// ---------------- BN stats / fused normalize ----------------
__global__ __launch_bounds__(256) void colstats(const float* __restrict__ H,
                                                float* __restrict__ cs, float* __restrict__ csq) {
    const int tid = threadIdx.x;
    const int c4 = (tid & 127) * 4;
    const int ro = tid >> 7;                 // 0/1
    const int r0 = blockIdx.x * 32;          // 128 blocks x 32 rows
    float s0 = 0, s1 = 0, s2 = 0, s3 = 0, q0 = 0, q1 = 0, q2 = 0, q3 = 0;
#pragma unroll
    for (int i = 0; i < 16; ++i) {
        float4 v = *(const float4*)&H[(size_t)(r0 + ro + 2 * i) * NP + c4];
        s0 += v.x; q0 += v.x * v.x;  s1 += v.y; q1 += v.y * v.y;
        s2 += v.z; q2 += v.z * v.z;  s3 += v.w; q3 += v.w * v.w;
    }
    atomicAdd(&cs[c4], s0); atomicAdd(&cs[c4 + 1], s1);
    atomicAdd(&cs[c4 + 2], s2); atomicAdd(&cs[c4 + 3], s3);
    atomicAdd(&csq[c4], q0); atomicAdd(&csq[c4 + 1], q1);
    atomicAdd(&csq[c4 + 2], q2); atomicAdd(&csq[c4 + 3], q3);
}

__global__ __launch_bounds__(256) void bnrelu(const float* __restrict__ H,
                       const float* __restrict__ cs, const float* __restrict__ csq,
                       const float* __restrict__ g, const float* __restrict__ be,
                       unsigned short* __restrict__ O) {
    __shared__ float sc[NP], sh[NP];
    for (int c = threadIdx.x; c < NP; c += 256) {
        float mean = cs[c] * (1.f / 4096.f);
        float var  = csq[c] * (1.f / 4096.f) - mean * mean;
        float s = (c < HID ? g[c] : 0.f) * rsqrtf(var + 1e-5f);
        sc[c] = s;
        sh[c] = (c < HID ? be[c] : 0.f) - mean * s;
    }
    __syncthreads();
    const size_t n4 = (size_t)B_ROWS * NP / 4;
    const size_t stride = (size_t)gridDim.x * 256;
    for (size_t i = (size_t)blockIdx.x * 256 + threadIdx.x; i < n4; i += stride) {
        const int c = (int)(i & 127) * 4;
        float4 v = ((const float4*)H)[i];
        unsigned short u0 = f2bf(fmaxf(v.x * sc[c]     + sh[c],     0.f));
        unsigned short u1 = f2bf(fmaxf(v.y * sc[c + 1] + sh[c + 1], 0.f));
        unsigned short u2 = f2bf(fmaxf(v.z * sc[c + 2] + sh[c + 2], 0.f));
        unsigned short u3 = f2bf(fmaxf(v.w * sc[c + 3] + sh[c + 3], 0.f));
        uint2 pk; pk.x = u0 | ((unsigned)u1 << 16); pk.y = u2 | ((unsigned)u3 << 16);
        *(uint2*)&O[i * 4] = pk;
    }
}

// ---- layer-2 variant: bn+relu fused directly into the final dot (no hn write) ----
__global__ __launch_bounds__(256) void bnrelu_dot(const float* __restrict__ H,
                       const float* __restrict__ cs, const float* __restrict__ csq,
                       const float* __restrict__ g, const float* __restrict__ be,
                       const float* __restrict__ w3, const float* __restrict__ b3,
                       float* __restrict__ out) {
    __shared__ float sc[NP], sh[NP], ww[NP];
    for (int c = threadIdx.x; c < NP; c += 256) {
        float mean = cs[c] * (1.f / 4096.f);
        float var  = csq[c] * (1.f / 4096.f) - mean * mean;
        float s = (c < HID ? g[c] : 0.f) * rsqrtf(var + 1e-5f);
        sc[c] = s;
        sh[c] = (c < HID ? be[c] : 0.f) - mean * s;
        ww[c] = (c < HID ? w3[c] : 0.f);
    }
    __syncthreads();
    const float b0 = b3[0];
    const int ln = threadIdx.x & 63;
    const size_t n4 = (size_t)B_ROWS * NP / 4;
    const size_t stride = (size_t)gridDim.x * 256;
    for (size_t i = (size_t)blockIdx.x * 256 + threadIdx.x; i < n4; i += stride) {
        const int c = (int)(i & 127) * 4;
        const int row = (int)(i >> 7);       // wave-uniform (64-aligned i-range within 128-chunk)
        float4 v = ((const float4*)H)[i];
        float s = fmaxf(v.x * sc[c]     + sh[c],     0.f) * ww[c]
                + fmaxf(v.y * sc[c + 1] + sh[c + 1], 0.f) * ww[c + 1]
                + fmaxf(v.z * sc[c + 2] + sh[c + 2], 0.f) * ww[c + 2]
                + fmaxf(v.w * sc[c + 3] + sh[c + 3], 0.f) * ww[c + 3];
#pragma unroll
        for (int o = 32; o; o >>= 1) s += __shfl_down(s, o);
        if (ln == 0) {
            if ((i & 127) == 0) s += b0;     // add bias exactly once per row
            atomicAdd(&out[row], s);
        }
    }
}

// ---------------- launch ----------------
extern "C" void kernel_launch(void* const* d_in, const int* in_sizes, int n_in,
                              void* d_out, int out_size, void* d_ws, size_t ws_size,
                              hipStream_t stream)
{
    const int*   x    = (const int*)d_in[0];
    const float* emb  = (const float*)d_in[1];
    const float* sw1  = (const float*)d_in[2];
    const float* sb1  = (const float*)d_in[3];
    const float* sw2  = (const float*)d_in[4];
    const float* sb2  = (const float*)d_in[5];
    const float* Wb1  = (const float*)d_in[6];
    const float* Wb2  = (const float*)d_in[7];
    const float* mw0  = (const float*)d_in[8];
    const float* g0   = (const float*)d_in[10];
    const float* be0  = (const float*)d_in[11];
    const float* mw1  = (const float*)d_in[12];
    const float* g1   = (const float*)d_in[14];
    const float* be1  = (const float*)d_in[15];
    const float* mw2  = (const float*)d_in[16];
    const float* g2   = (const float*)d_in[18];
    const float* be2  = (const float*)d_in[19];
    const float* mw3  = (const float*)d_in[20];
    const float* mb3  = (const float*)d_in[21];
    (void)in_sizes; (void)n_in; (void)out_size;
    if (ws_size < WS_NEEDED) return;

    char* ws = (char*)d_ws;
    unsigned short* xcon = (unsigned short*)(ws + OFF_XCON);
    unsigned short* w0b  = (unsigned short*)(ws + OFF_W0B);
    unsigned short* w1b  = (unsigned short*)(ws + OFF_W1B);
    unsigned short* w2b  = (unsigned short*)(ws + OFF_W2B);
    float* hpre = (float*)(ws + OFF_HPRE);
    unsigned short* hn = (unsigned short*)(ws + OFF_HN);
    float* cs  = (float*)(ws + OFF_STATS);
    float* csq = cs + 512;

    build_xcon<<<B_ROWS, 256, 0, stream>>>(x, emb, sw1, sb1, sw2, sb2, Wb1, Wb2, xcon);
    cvt_w0<<<NP, 256, 0, stream>>>(mw0, w0b);
    cvt_wsm<<<2 * NP, 256, 0, stream>>>(mw1, mw2, w1b, w2b);

    // layer 0: split-K GEMM (64x256 tiles, 1024 blocks = 4/CU) with atomic accumulation
    hipMemsetAsync(hpre, 0, SZ_HPRE, stream);
    gemm0<<<dim3(NP / 256, B_ROWS / 64, SPLITK0), 256, 0, stream>>>(
        xcon, w0b, hpre, (KITERS0 + SPLITK0 - 1) / SPLITK0);

    auto bn = [&](const float* g, const float* be) {
        hipMemsetAsync(cs, 0, 4096, stream);
        colstats<<<128, 256, 0, stream>>>(hpre, cs, csq);
        bnrelu<<<512, 256, 0, stream>>>(hpre, cs, csq, g, be, hn);
    };
    bn(g0, be0);
    gemm_small<<<dim3(NP / 64, B_ROWS / 64), 256, 0, stream>>>(hn, w1b, hpre);
    bn(g1, be1);
    gemm_small<<<dim3(NP / 64, B_ROWS / 64), 256, 0, stream>>>(hn, w2b, hpre);
    // layer 2 BN + relu + final dot fused
    hipMemsetAsync(cs, 0, 4096, stream);
    colstats<<<128, 256, 0, stream>>>(hpre, cs, csq);
    hipMemsetAsync(d_out, 0, (size_t)B_ROWS * 4, stream);
    bnrelu_dot<<<512, 256, 0, stream>>>(hpre, cs, csq, g2, be2, mw3, mb3, (float*)d_out);
}

// Round 4
// 377.836 us; speedup vs baseline: 1.2808x; 1.2808x over previous
//
#include <hip/hip_runtime.h>
#include <stdint.h>

// ---------------- problem constants ----------------
#define B_ROWS  4096
#define F_FIELDS 39
#define NPAIR   741
#define XCON_K  23712          // 2*741*16
#define KP      23744          // padded to multiple of 64
#define NP      512            // padded hidden width (real 400)
#define HID     400
#define SPLITK0 8
#define KITERS0 (KP/64)        // 371

// ---------------- ws layout (bytes) ----------------
#define OFF_XCON 0ull
#define SZ_XCON  ((size_t)B_ROWS * KP * 2)        // 194,510,848
#define OFF_W0B  (OFF_XCON + SZ_XCON)
#define SZ_W0B   ((size_t)NP * KP * 2)            // 24,313,856
#define OFF_W1B  (OFF_W0B + SZ_W0B)
#define SZ_WSM   ((size_t)NP * NP * 2)            // 524,288
#define OFF_W2B  (OFF_W1B + SZ_WSM)
#define OFF_HPRE (OFF_W2B + SZ_WSM)
#define SZ_HPRE  ((size_t)B_ROWS * NP * 4)        // 8,388,608
#define OFF_HN   (OFF_HPRE + SZ_HPRE)
#define SZ_HN    ((size_t)B_ROWS * NP * 2)        // 4,194,304
#define OFF_STATS (OFF_HN + SZ_HN)                // 6 x 512 f32 (cs/csq x 3 layers)
#define SZ_STATS  (6 * 512 * 4)
#define WS_NEEDED (OFF_STATS + SZ_STATS + 4096)

// ---------------- helpers ----------------
__device__ __forceinline__ unsigned short f2bf(float f) {
    union { float f; unsigned u; } v; v.f = f;
    unsigned r = (v.u + 0x7FFFu + ((v.u >> 16) & 1u)) >> 16;
    return (unsigned short)r;
}
__device__ __forceinline__ void gl_lds16(const void* g, void* l) {
    __builtin_amdgcn_global_load_lds(
        (const __attribute__((address_space(1))) void*)g,
        (__attribute__((address_space(3))) void*)l, 16, 0, 0);
}

typedef __bf16 bf16x8 __attribute__((ext_vector_type(8)));
typedef float  floatx4 __attribute__((ext_vector_type(4)));

// ============ fused: build_xcon (4096 blocks) + cvt_w0 (512) + cvt_wsm (1024) ============
__global__ __launch_bounds__(256) void build_all(
    const int* __restrict__ x, const float* __restrict__ emb,
    const float* __restrict__ w1, const float* __restrict__ b1,
    const float* __restrict__ w2, const float* __restrict__ b2,
    const float* __restrict__ Wb1, const float* __restrict__ Wb2,
    unsigned short* __restrict__ xcon,
    const float* __restrict__ mw0, unsigned short* __restrict__ w0b,
    const float* __restrict__ mw1, const float* __restrict__ mw2,
    unsigned short* __restrict__ w1b, unsigned short* __restrict__ w2b)
{
    __shared__ float xe[624], pp[2][624];
    __shared__ float zz[40], tt[40], aa[40];
    __shared__ short itab[NPAIR], jtab[NPAIR];
    const int bb = blockIdx.x, tid = threadIdx.x;

    if (bb >= B_ROWS) {
        if (bb < B_ROWS + NP) {
            // ---- cvt_w0: mw0 (400 x 23712 f32) -> w0b (512 x 23744 bf16, padded) ----
            const int o = bb - B_ROWS;
            for (int k4 = tid; k4 < KP / 4; k4 += 256) {
                const int k = k4 * 4;
                unsigned short u[4] = {0, 0, 0, 0};
                if (o < HID && k < XCON_K) {
                    float4 v = *(const float4*)&mw0[(size_t)o * XCON_K + k];
                    u[0] = f2bf(v.x); u[1] = f2bf(v.y); u[2] = f2bf(v.z); u[3] = f2bf(v.w);
                }
                uint2 pk; pk.x = u[0] | ((unsigned)u[1] << 16); pk.y = u[2] | ((unsigned)u[3] << 16);
                *(uint2*)&w0b[(size_t)o * KP + k] = pk;
            }
        } else {
            // ---- cvt_wsm: mw1/mw2 (400x400) -> w1b/w2b (512x512 bf16, padded) ----
            const int idx = bb - B_ROWS - NP;
            const int which = idx >> 9;
            const int o = idx & 511;
            const float* w = which ? mw2 : mw1;
            unsigned short* o_ = which ? w2b : w1b;
            for (int k = tid; k < NP; k += 256) {
                float v = (o < HID && k < HID) ? w[o * HID + k] : 0.f;
                o_[o * NP + k] = f2bf(v);
            }
        }
        return;
    }

    const int b = bb;
    // pair tables: cum(i) = i*(77-i)/2, j = i+1 + (p - cum(i))
    for (int p = tid; p < NPAIR; p += 256) {
        float fp = (float)p;
        int i = (int)(38.5f - sqrtf(38.5f * 38.5f - 2.f * fp));
        while (i > 0 && p < (i * (77 - i)) / 2) --i;
        while (p >= ((i + 1) * (76 - i)) / 2) ++i;
        itab[p] = (short)i;
        jtab[p] = (short)(i + 1 + (p - (i * (77 - i)) / 2));
    }
    if (tid < 156) {
        int f = tid >> 2, e4 = (tid & 3) * 4;
        int row = x[b * F_FIELDS + f] + 1000 * f;
        *(float4*)&xe[f * 16 + e4] = *(const float4*)&emb[row * 16 + e4];
    }
    __syncthreads();
    if (tid < F_FIELDS) {
        float m = xe[tid * 16];
        for (int e = 1; e < 16; ++e) m = fmaxf(m, xe[tid * 16 + e]);
        zz[tid] = m;
    }
    __syncthreads();
    if (tid < F_FIELDS) {
        float s = b1[tid];
        for (int g = 0; g < F_FIELDS; ++g) s += zz[g] * w1[tid * F_FIELDS + g];
        tt[tid] = fmaxf(s, 0.f);
    }
    __syncthreads();
    if (tid < F_FIELDS) {
        float s = b2[tid];
        for (int g = 0; g < F_FIELDS; ++g) s += tt[g] * w2[tid * F_FIELDS + g];
        aa[tid] = fmaxf(s, 0.f);
    }
    __syncthreads();
    for (int idx = tid; idx < 624; idx += 256) {
        int f = idx >> 4, d = idx & 15;
        float s1 = 0.f, s2 = 0.f;
        for (int e = 0; e < 16; ++e) {
            float v = xe[f * 16 + e];
            s1 += v * Wb1[d * 16 + e];
            s2 += v * Wb2[d * 16 + e];
        }
        pp[0][idx] = s1; pp[1][idx] = s2;
    }
    __syncthreads();
    unsigned short* out = xcon + (size_t)b * KP;
    for (int c = tid; c < 1484; c += 256) {
        if (c < 2 * NPAIR) {
            const int half = (c >= NPAIR);
            const int p = c - NPAIR * half;
            const int i = itab[p], j = jtab[p];
            const float f = half ? aa[i] * aa[j] : 1.f;
            const float* pr = &pp[half][i * 16];
            const float* xr = &xe[j * 16];
            unsigned short u[16];
#pragma unroll
            for (int e = 0; e < 16; ++e) u[e] = f2bf(f * pr[e] * xr[e]);
            uint4 v0, v1;
            v0.x = u[0] | ((unsigned)u[1] << 16);  v0.y = u[2] | ((unsigned)u[3] << 16);
            v0.z = u[4] | ((unsigned)u[5] << 16);  v0.w = u[6] | ((unsigned)u[7] << 16);
            v1.x = u[8] | ((unsigned)u[9] << 16);  v1.y = u[10] | ((unsigned)u[11] << 16);
            v1.z = u[12] | ((unsigned)u[13] << 16); v1.w = u[14] | ((unsigned)u[15] << 16);
            uint4* dst = (uint4*)(out + (half ? 11856 : 0) + p * 16);
            dst[0] = v0; dst[1] = v1;
        } else {
            uint4 z; z.x = z.y = z.z = z.w = 0u;
            ((uint4*)(out + XCON_K))[c - 2 * NPAIR] = z;
        }
    }
}

// ============ GEMM0: 128x256 tile, split-K, XOR-swizzled LDS, atomic f32 epilogue ============
// C[4096,512] += A[4096,KP] @ B[512,KP]^T ; 4 waves (2x2), wave tile 64x128 (4x8 MFMAs)
// LDS rows are 64 bf16 = 128 B; chunk (16 B) c of row r stored at physical chunk c^(r&7)
// -> fragment reads hit all 32 banks with 2-way aliasing (free) instead of 8-16-way.
__global__ __launch_bounds__(256, 2) void gemm0(
    const unsigned short* __restrict__ A, const unsigned short* __restrict__ Bm,
    float* __restrict__ C, int kcnt)
{
    __shared__ __align__(16) unsigned short As[128 * 64];    // 16 KB
    __shared__ __align__(16) unsigned short Bs[256 * 64];    // 32 KB
    const int tid = threadIdx.x;
    const int m0 = blockIdx.y * 128, n0 = blockIdx.x * 256;
    int kb = blockIdx.z * kcnt;
    int ke = kb + kcnt; if (ke > KITERS0) ke = KITERS0;

    // staging: lane (row=tid>>3, lds chunk=tid&7) fetches GLOBAL chunk (tid&7)^(row&7)
    const int swz = (((tid & 7) ^ ((tid >> 3) & 7)) * 8);
    const unsigned short* Ag = A + (size_t)(m0 + (tid >> 3)) * KP + swz;
    const unsigned short* Bg = Bm + (size_t)(n0 + (tid >> 3)) * KP + swz;
    unsigned short* Asl = As + tid * 8;
    unsigned short* Bsl = Bs + tid * 8;

    const int wv = tid >> 6, ln = tid & 63;
    const int wm = (wv >> 1) * 64, wn = (wv & 1) * 128;
    const int l15 = ln & 15, lq = ln >> 4;
    const int xorm = l15 & 7;

    floatx4 acc[4][8];
#pragma unroll
    for (int mi = 0; mi < 4; ++mi)
#pragma unroll
        for (int ni = 0; ni < 8; ++ni)
            acc[mi][ni] = (floatx4){0.f, 0.f, 0.f, 0.f};

    for (int kt = kb; kt < ke; ++kt) {
        const size_t ko = (size_t)kt * 64;
#pragma unroll
        for (int i = 0; i < 4; ++i)
            gl_lds16(Ag + (size_t)(i * 32) * KP + ko, Asl + i * 2048);
#pragma unroll
        for (int i = 0; i < 8; ++i)
            gl_lds16(Bg + (size_t)(i * 32) * KP + ko, Bsl + i * 2048);
        __syncthreads();
#pragma unroll
        for (int kk = 0; kk < 64; kk += 32) {
            bf16x8 af[4], bfr[8];
#pragma unroll
            for (int t = 0; t < 4; ++t)
                af[t] = *(const bf16x8*)(As + (wm + t * 16 + l15) * 64
                                            + ((((kk >> 3) + lq) ^ xorm) * 8));
#pragma unroll
            for (int t = 0; t < 8; ++t)
                bfr[t] = *(const bf16x8*)(Bs + (wn + t * 16 + l15) * 64
                                             + ((((kk >> 3) + lq) ^ xorm) * 8));
#pragma unroll
            for (int mi = 0; mi < 4; ++mi)
#pragma unroll
                for (int ni = 0; ni < 8; ++ni)
                    acc[mi][ni] = __builtin_amdgcn_mfma_f32_16x16x32_bf16(
                        af[mi], bfr[ni], acc[mi][ni], 0, 0, 0);
        }
        __syncthreads();
    }
#pragma unroll
    for (int mi = 0; mi < 4; ++mi)
#pragma unroll
        for (int ni = 0; ni < 8; ++ni) {
            const int col = n0 + wn + ni * 16 + l15;
            const int row0 = m0 + wm + mi * 16 + lq * 4;
#pragma unroll
            for (int r = 0; r < 4; ++r)
                atomicAdd(&C[(size_t)(row0 + r) * NP + col], acc[mi][ni][r]);
        }
}

// ============ GEMM1/2: 64x64 tile, K=512, swizzled LDS, direct store + fused col-stats ============
__global__ __launch_bounds__(256) void gemm_small(
    const unsigned short* __restrict__ A, const unsigned short* __restrict__ Bm,
    float* __restrict__ C, float* __restrict__ cs, float* __restrict__ csq)
{
    __shared__ __align__(16) unsigned short As[64 * 64];
    __shared__ __align__(16) unsigned short Bs[64 * 64];
    const int tid = threadIdx.x;
    const int m0 = blockIdx.y * 64, n0 = blockIdx.x * 64;

    const int swz = (((tid & 7) ^ ((tid >> 3) & 7)) * 8);
    const unsigned short* Ag = A + (size_t)(m0 + (tid >> 3)) * NP + swz;
    const unsigned short* Bg = Bm + (size_t)(n0 + (tid >> 3)) * NP + swz;
    unsigned short* Asl = As + tid * 8;
    unsigned short* Bsl = Bs + tid * 8;

    const int wv = tid >> 6, ln = tid & 63;
    const int wm = (wv >> 1) * 32, wn = (wv & 1) * 32;
    const int l15 = ln & 15, lq = ln >> 4;
    const int xorm = l15 & 7;

    floatx4 acc[2][2];
#pragma unroll
    for (int mi = 0; mi < 2; ++mi)
#pragma unroll
        for (int ni = 0; ni < 2; ++ni)
            acc[mi][ni] = (floatx4){0.f, 0.f, 0.f, 0.f};

    for (int kt = 0; kt < NP / 64; ++kt) {
        const size_t ko = (size_t)kt * 64;
#pragma unroll
        for (int i = 0; i < 2; ++i) {
            gl_lds16(Ag + (size_t)(i * 32) * NP + ko, Asl + i * 2048);
            gl_lds16(Bg + (size_t)(i * 32) * NP + ko, Bsl + i * 2048);
        }
        __syncthreads();
#pragma unroll
        for (int kk = 0; kk < 64; kk += 32) {
            bf16x8 af[2], bfr[2];
#pragma unroll
            for (int t = 0; t < 2; ++t) {
                af[t]  = *(const bf16x8*)(As + (wm + t * 16 + l15) * 64
                                             + ((((kk >> 3) + lq) ^ xorm) * 8));
                bfr[t] = *(const bf16x8*)(Bs + (wn + t * 16 + l15) * 64
                                             + ((((kk >> 3) + lq) ^ xorm) * 8));
            }
#pragma unroll
            for (int mi = 0; mi < 2; ++mi)
#pragma unroll
                for (int ni = 0; ni < 2; ++ni)
                    acc[mi][ni] = __builtin_amdgcn_mfma_f32_16x16x32_bf16(
                        af[mi], bfr[ni], acc[mi][ni], 0, 0, 0);
        }
        __syncthreads();
    }
#pragma unroll
    for (int mi = 0; mi < 2; ++mi)
#pragma unroll
        for (int ni = 0; ni < 2; ++ni) {
            const int col = n0 + wn + ni * 16 + l15;
            const int row0 = m0 + wm + mi * 16 + lq * 4;
#pragma unroll
            for (int r = 0; r < 4; ++r)
                C[(size_t)(row0 + r) * NP + col] = acc[mi][ni][r];
        }
    // fused column stats: wave covers 32 rows of each of its 32 columns
#pragma unroll
    for (int ni = 0; ni < 2; ++ni) {
        float s = 0.f, q = 0.f;
#pragma unroll
        for (int mi = 0; mi < 2; ++mi)
#pragma unroll
            for (int r = 0; r < 4; ++r) { float v = acc[mi][ni][r]; s += v; q += v * v; }
        s += __shfl_down(s, 32); q += __shfl_down(q, 32);
        s += __shfl_down(s, 16); q += __shfl_down(q, 16);
        if (lq == 0) {
            const int col = n0 + wn + ni * 16 + l15;
            atomicAdd(&cs[col], s);
            atomicAdd(&csq[col], q);
        }
    }
}

// ============ BN stats for layer 0 (after split-K atomics) ============
__global__ __launch_bounds__(256) void colstats(const float* __restrict__ H,
                                                float* __restrict__ cs, float* __restrict__ csq) {
    const int tid = threadIdx.x;
    const int c4 = (tid & 127) * 4;
    const int ro = tid >> 7;
    const int r0 = blockIdx.x * 32;
    float s0 = 0, s1 = 0, s2 = 0, s3 = 0, q0 = 0, q1 = 0, q2 = 0, q3 = 0;
#pragma unroll
    for (int i = 0; i < 16; ++i) {
        float4 v = *(const float4*)&H[(size_t)(r0 + ro + 2 * i) * NP + c4];
        s0 += v.x; q0 += v.x * v.x;  s1 += v.y; q1 += v.y * v.y;
        s2 += v.z; q2 += v.z * v.z;  s3 += v.w; q3 += v.w * v.w;
    }
    atomicAdd(&cs[c4], s0); atomicAdd(&cs[c4 + 1], s1);
    atomicAdd(&cs[c4 + 2], s2); atomicAdd(&cs[c4 + 3], s3);
    atomicAdd(&csq[c4], q0); atomicAdd(&csq[c4 + 1], q1);
    atomicAdd(&csq[c4 + 2], q2); atomicAdd(&csq[c4 + 3], q3);
}

// ============ BN + relu + bf16 cast ============
__global__ __launch_bounds__(256) void bnrelu(const float* __restrict__ H,
                       const float* __restrict__ cs, const float* __restrict__ csq,
                       const float* __restrict__ g, const float* __restrict__ be,
                       unsigned short* __restrict__ O) {
    __shared__ float sc[NP], sh[NP];
    for (int c = threadIdx.x; c < NP; c += 256) {
        float mean = cs[c] * (1.f / 4096.f);
        float var  = csq[c] * (1.f / 4096.f) - mean * mean;
        float s = (c < HID ? g[c] : 0.f) * rsqrtf(var + 1e-5f);
        sc[c] = s;
        sh[c] = (c < HID ? be[c] : 0.f) - mean * s;
    }
    __syncthreads();
    const size_t n4 = (size_t)B_ROWS * NP / 4;
    const size_t stride = (size_t)gridDim.x * 256;
    for (size_t i = (size_t)blockIdx.x * 256 + threadIdx.x; i < n4; i += stride) {
        const int c = (int)(i & 127) * 4;
        float4 v = ((const float4*)H)[i];
        unsigned short u0 = f2bf(fmaxf(v.x * sc[c]     + sh[c],     0.f));
        unsigned short u1 = f2bf(fmaxf(v.y * sc[c + 1] + sh[c + 1], 0.f));
        unsigned short u2 = f2bf(fmaxf(v.z * sc[c + 2] + sh[c + 2], 0.f));
        unsigned short u3 = f2bf(fmaxf(v.w * sc[c + 3] + sh[c + 3], 0.f));
        uint2 pk; pk.x = u0 | ((unsigned)u1 << 16); pk.y = u2 | ((unsigned)u3 << 16);
        *(uint2*)&O[i * 4] = pk;
    }
}

// ============ layer-2 BN + relu + final dot, one wave per row, direct store ============
__global__ __launch_bounds__(256) void bnrelu_dot(const float* __restrict__ H,
                       const float* __restrict__ cs, const float* __restrict__ csq,
                       const float* __restrict__ g, const float* __restrict__ be,
                       const float* __restrict__ w3, const float* __restrict__ b3,
                       float* __restrict__ out) {
    __shared__ float sc[NP], sh[NP], ww[NP];
    for (int c = threadIdx.x; c < NP; c += 256) {
        float mean = cs[c] * (1.f / 4096.f);
        float var  = csq[c] * (1.f / 4096.f) - mean * mean;
        float s = (c < HID ? g[c] : 0.f) * rsqrtf(var + 1e-5f);
        sc[c] = s;
        sh[c] = (c < HID ? be[c] : 0.f) - mean * s;
        ww[c] = (c < HID ? w3[c] : 0.f);
    }
    __syncthreads();
    const int wv = threadIdx.x >> 6, ln = threadIdx.x & 63;
    const int row = blockIdx.x * 4 + wv;
    const float4* hp = (const float4*)(H + (size_t)row * NP);
    float s = 0.f;
#pragma unroll
    for (int it = 0; it < 2; ++it) {
        const int c4 = it * 64 + ln;
        const int c = c4 * 4;
        float4 v = hp[c4];
        s += fmaxf(v.x * sc[c]     + sh[c],     0.f) * ww[c]
           + fmaxf(v.y * sc[c + 1] + sh[c + 1], 0.f) * ww[c + 1]
           + fmaxf(v.z * sc[c + 2] + sh[c + 2], 0.f) * ww[c + 2]
           + fmaxf(v.w * sc[c + 3] + sh[c + 3], 0.f) * ww[c + 3];
    }
#pragma unroll
    for (int o = 32; o; o >>= 1) s += __shfl_down(s, o);
    if (ln == 0) out[row] = s + b3[0];
}

// ---------------- launch ----------------
extern "C" void kernel_launch(void* const* d_in, const int* in_sizes, int n_in,
                              void* d_out, int out_size, void* d_ws, size_t ws_size,
                              hipStream_t stream)
{
    const int*   x    = (const int*)d_in[0];
    const float* emb  = (const float*)d_in[1];
    const float* sw1  = (const float*)d_in[2];
    const float* sb1  = (const float*)d_in[3];
    const float* sw2  = (const float*)d_in[4];
    const float* sb2  = (const float*)d_in[5];
    const float* Wb1  = (const float*)d_in[6];
    const float* Wb2  = (const float*)d_in[7];
    const float* mw0  = (const float*)d_in[8];
    const float* g0   = (const float*)d_in[10];
    const float* be0  = (const float*)d_in[11];
    const float* mw1  = (const float*)d_in[12];
    const float* g1   = (const float*)d_in[14];
    const float* be1  = (const float*)d_in[15];
    const float* mw2  = (const float*)d_in[16];
    const float* g2   = (const float*)d_in[18];
    const float* be2  = (const float*)d_in[19];
    const float* mw3  = (const float*)d_in[20];
    const float* mb3  = (const float*)d_in[21];
    (void)in_sizes; (void)n_in; (void)out_size;
    if (ws_size < WS_NEEDED) return;

    char* ws = (char*)d_ws;
    unsigned short* xcon = (unsigned short*)(ws + OFF_XCON);
    unsigned short* w0b  = (unsigned short*)(ws + OFF_W0B);
    unsigned short* w1b  = (unsigned short*)(ws + OFF_W1B);
    unsigned short* w2b  = (unsigned short*)(ws + OFF_W2B);
    float* hpre = (float*)(ws + OFF_HPRE);
    unsigned short* hn = (unsigned short*)(ws + OFF_HN);
    float* stats = (float*)(ws + OFF_STATS);
    float* cs0 = stats,        *csq0 = stats + 512;
    float* cs1 = stats + 1024, *csq1 = stats + 1536;
    float* cs2 = stats + 2048, *csq2 = stats + 2560;

    // one fused prep kernel: xcon build + all weight conversions
    build_all<<<B_ROWS + NP + 2 * NP, 256, 0, stream>>>(
        x, emb, sw1, sb1, sw2, sb2, Wb1, Wb2, xcon, mw0, w0b, mw1, mw2, w1b, w2b);

    hipMemsetAsync(hpre, 0, SZ_HPRE, stream);
    hipMemsetAsync(stats, 0, SZ_STATS, stream);

    // layer 0: split-K GEMM (128x256 tiles, 512 blocks = 2/CU)
    gemm0<<<dim3(NP / 256, B_ROWS / 128, SPLITK0), 256, 0, stream>>>(
        xcon, w0b, hpre, (KITERS0 + SPLITK0 - 1) / SPLITK0);
    colstats<<<128, 256, 0, stream>>>(hpre, cs0, csq0);
    bnrelu<<<512, 256, 0, stream>>>(hpre, cs0, csq0, g0, be0, hn);

    // layer 1 (stats fused into epilogue)
    gemm_small<<<dim3(NP / 64, B_ROWS / 64), 256, 0, stream>>>(hn, w1b, hpre, cs1, csq1);
    bnrelu<<<512, 256, 0, stream>>>(hpre, cs1, csq1, g1, be1, hn);

    // layer 2 (stats fused) + BN/relu/dot fused, direct store
    gemm_small<<<dim3(NP / 64, B_ROWS / 64), 256, 0, stream>>>(hn, w2b, hpre, cs2, csq2);
    bnrelu_dot<<<B_ROWS / 4, 256, 0, stream>>>(hpre, cs2, csq2, g2, be2, mw3, mb3, (float*)d_out);
}